// Round 4
// baseline (83.525 us; speedup 1.0000x reference)
//
#include <hip/hip_runtime.h>

// MMD loss, atomic-free, 128x128 tiles. ws layout:
//   [0, 16640)        float2 partial[<=2080]  per-block {S_same, S_all}
//   [16640, 82176)    float  sqpart[4][N]     row-norm partials per k-quarter
//   [82176, +2*N*D)   uint4  fbt[N*D/8]       bf16 feature, TILED k-major:
//        chunk (rt, kc, r) -> index rt*(D/8)*64 + kc*64 + r   (16B chunks)
//        holds feature[rt*64 + r][kc*8 .. kc*8+8) as bf16

typedef __attribute__((ext_vector_type(8))) short short8;
typedef __attribute__((ext_vector_type(4))) float floatx4;

#define AS1 __attribute__((address_space(1)))
#define AS3 __attribute__((address_space(3)))

__device__ inline unsigned f2bf2(float lo, float hi) {
  union { float f; unsigned u; } a, b; a.f = lo; b.f = hi;
  unsigned ra = (a.u + 0x7fffu + ((a.u >> 16) & 1u)) >> 16;
  unsigned rb = (b.u + 0x7fffu + ((b.u >> 16) & 1u)) >> 16;
  return ra | (rb << 16);
}

__device__ inline float fast_exp2(float x) {
#if __has_builtin(__builtin_amdgcn_exp2f)
  return __builtin_amdgcn_exp2f(x);
#else
  return exp2f(x);
#endif
}

// Grid: (N/64)*4 blocks; block (rt, kq) writes 64 rows x 64 cols of fbt,
// fully coalesced. Row-norm partials per kq; no atomics.
__global__ __launch_bounds__(256) void prep_kernel(
    const float* __restrict__ feat, uint4* __restrict__ fbt,
    float* __restrict__ sqpart, int N, int D) {
  const int tid = threadIdx.x;
  const int rt = blockIdx.x >> 2;
  const int kq = blockIdx.x & 3;
  const int r = tid & 63;
  const int nkc = D >> 3;
  __shared__ float sqp[256];
  float ss = 0.f;
  #pragma unroll
  for (int it = 0; it < 2; ++it) {
    const int kc = kq * 8 + it * 4 + (tid >> 6);
    const float4* src = (const float4*)(feat + (size_t)(rt * 64 + r) * D + kc * 8);
    float4 v0 = src[0], v1 = src[1];
    ss += v0.x*v0.x + v0.y*v0.y + v0.z*v0.z + v0.w*v0.w
        + v1.x*v1.x + v1.y*v1.y + v1.z*v1.z + v1.w*v1.w;
    uint4 o;
    o.x = f2bf2(v0.x, v0.y); o.y = f2bf2(v0.z, v0.w);
    o.z = f2bf2(v1.x, v1.y); o.w = f2bf2(v1.z, v1.w);
    fbt[(size_t)rt * nkc * 64 + kc * 64 + r] = o;
  }
  sqp[tid] = ss;
  __syncthreads();
  if (tid < 64)
    sqpart[(size_t)kq * N + rt * 64 + tid] =
        sqp[tid] + sqp[tid + 64] + sqp[tid + 128] + sqp[tid + 192];
}

// One 128x128 tile pair per block (upper triangle of 32x32 tile grid).
// 512 thr = 8 waves; wave w owns rows [w*16, w*16+16), all 128 cols.
// A frags in regs; 64KB B tile staged once via global_load_lds; 1 barrier.
__global__ __launch_bounds__(512, 4) void mmd_main(
    const uint4* __restrict__ fbt, const float* __restrict__ sqpart,
    const int* __restrict__ dom, float2* __restrict__ partial, int N) {
  int b = blockIdx.x;
  int i = (int)((sqrtf(8.f * (float)b + 1.f) - 1.f) * 0.5f);
  while ((i + 1) * (i + 2) / 2 <= b) ++i;
  while (i * (i + 1) / 2 > b) --i;
  const int ti = b - i * (i + 1) / 2;
  const int tj = i;
  const int rowI = ti * 128, rowJ = tj * 128;

  __shared__ __align__(16) uint4 Bs[4096];    // 64 KB, two 64-row subtiles
  __shared__ float sqI[128], sqJ[128];
  __shared__ int dmI[128], dmJ[128];
  __shared__ float red[16];

  const int tid = threadIdx.x;
  const int lane = tid & 63, w = tid >> 6;
  const int quad = lane >> 4, m16 = lane & 15;

  const uint4* At = fbt + (size_t)ti * 4096;
  const uint4* Bt = fbt + (size_t)tj * 4096;

  // stage B: 4096 chunks, 8 per thread, wave-contiguous (lane-stride 16B)
  #pragma unroll
  for (int p = 0; p < 8; ++p) {
    const int base = p * 512 + w * 64;
#if __has_builtin(__builtin_amdgcn_global_load_lds)
    __builtin_amdgcn_global_load_lds(
        (const AS1 uint4*)(Bt + base + lane),
        (AS3 uint4*)(Bs + base), 16, 0, 0);
#else
    Bs[base + lane] = Bt[base + lane];
#endif
  }

  // A fragments: wave w -> subtile (w>>2), rows (w&3)*16 + m16
  short8 afrag[8];
  {
    const uint4* Aw = At + (size_t)(w >> 2) * 2048 + (w & 3) * 16 + m16;
    #pragma unroll
    for (int s = 0; s < 8; ++s) {
      uint4 t = Aw[(s * 4 + quad) * 64];
      afrag[s] = *(short8*)&t;
    }
  }

  if (tid < 128) {
    sqI[tid] = sqpart[rowI + tid] + sqpart[N + rowI + tid]
             + sqpart[2 * N + rowI + tid] + sqpart[3 * N + rowI + tid];
    dmI[tid] = dom[rowI + tid];
  } else if (tid < 256) {
    int t = tid - 128;
    sqJ[t] = sqpart[rowJ + t] + sqpart[N + rowJ + t]
           + sqpart[2 * N + rowJ + t] + sqpart[3 * N + rowJ + t];
    dmJ[t] = dom[rowJ + t];
  }
  __syncthreads();   // drains global_load_lds + sq/dm visible

  floatx4 acc[8];
  #pragma unroll
  for (int t = 0; t < 8; ++t) acc[t] = (floatx4){0.f, 0.f, 0.f, 0.f};

  #pragma unroll
  for (int s = 0; s < 8; ++s) {
    #pragma unroll
    for (int t = 0; t < 8; ++t) {
      const uint4* bp = Bs + (size_t)(t >> 2) * 2048
                      + (s * 4 + quad) * 64 + (t & 3) * 16 + m16;
      uint4 bt = *bp;
      acc[t] = __builtin_amdgcn_mfma_f32_16x16x32_bf16(
                   afrag[s], *(short8*)&bt, acc[t], 0, 0, 0);
    }
  }

  // c_s = -0.5*log2(e)*sigma for sigma in {1e-4,1e-3,1e-2,0.1,1,5,100};
  // sigma 10..30 from powers of the sigma=5 exp.
  const float C0 = -7.2134752e-05f, C1 = -7.2134752e-04f, C2 = -7.2134752e-03f,
              C3 = -7.2134752e-02f, C4 = -0.72134752f, C5 = -3.6067376f,
              C100 = -72.13475204f;

  float s_all = 0.f, s_same = 0.f;
  const int r0 = w * 16 + quad * 4;
  float sqr[4]; int dmr[4];
  #pragma unroll
  for (int reg = 0; reg < 4; ++reg) { sqr[reg] = sqI[r0 + reg]; dmr[reg] = dmI[r0 + reg]; }

  #pragma unroll
  for (int t = 0; t < 8; ++t) {
    const int c = t * 16 + m16;                // C/D: col = lane&15
    const float sqc = sqJ[c];
    const int dc = dmJ[c];
    const int gj = rowJ + c;
    #pragma unroll
    for (int reg = 0; reg < 4; ++reg) {
      const int gi = rowI + r0 + reg;          // C/D: row = quad*4 + reg
      float d2 = sqr[reg] + sqc - 2.f * acc[t][reg];
      d2 = fmaxf(d2, 0.f);
      if (gi == gj) d2 = 0.f;                  // diagonal exact: k=12 dominates
      float e0 = fast_exp2(d2 * C0), e1 = fast_exp2(d2 * C1);
      float e2 = fast_exp2(d2 * C2), e3 = fast_exp2(d2 * C3);
      float e4 = fast_exp2(d2 * C4), e5 = fast_exp2(d2 * C5);
      float e11 = fast_exp2(d2 * C100);
      float t10 = e5 * e5, t15 = t10 * e5, t20 = t10 * t10;
      float t25 = t15 * t10, t30 = t15 * t15;
      float kk = ((e0 + e1) + (e2 + e3)) + ((e4 + e5) + (t10 + t15))
               + ((t20 + t25) + (t30 + e11));
      s_all += kk;
      if (dmr[reg] == dc) s_same += kk;
    }
  }
  #pragma unroll
  for (int off = 32; off > 0; off >>= 1) {
    s_all  += __shfl_down(s_all, off);
    s_same += __shfl_down(s_same, off);
  }
  if (lane == 0) { red[w] = s_all; red[8 + w] = s_same; }
  __syncthreads();
  if (tid == 0) {
    const float wt = (ti == tj) ? 1.f : 2.f;   // off-diag tiles count twice
    float a = 0.f, s = 0.f;
    #pragma unroll
    for (int k = 0; k < 8; ++k) { a += red[k]; s += red[8 + k]; }
    partial[b] = make_float2(s * wt, a * wt);
  }
}

__global__ __launch_bounds__(256) void finalize_kernel(
    const float2* __restrict__ partial, int nblk,
    const int* __restrict__ dom, float* __restrict__ out, int N) {
  __shared__ int histL[16];
  __shared__ double redS[8];
  const int tid = threadIdx.x;
  if (tid < 16) histL[tid] = 0;
  __syncthreads();
  for (int i = tid; i < N; i += 256) atomicAdd(&histL[dom[i] & 15], 1);
  double as = 0.0, aa = 0.0;
  for (int i = tid; i < nblk; i += 256) {
    float2 p = partial[i];
    as += (double)p.x; aa += (double)p.y;
  }
  #pragma unroll
  for (int off = 32; off > 0; off >>= 1) {
    as += __shfl_down(as, off);
    aa += __shfl_down(aa, off);
  }
  const int w = tid >> 6;
  if ((tid & 63) == 0) { redS[w] = as; redS[4 + w] = aa; }
  __syncthreads();
  if (tid == 0) {
    double S = redS[0] + redS[1] + redS[2] + redS[3];
    double A = redS[4] + redS[5] + redS[6] + redS[7];
    double csame = 0.0;
    for (int i = 0; i < 16; ++i) { double h = (double)histL[i]; csame += h * h; }
    double call = (double)N * (double)N;
    out[0] = (float)(S / csame - (A - S) / (call - csame));
  }
}

extern "C" void kernel_launch(void* const* d_in, const int* in_sizes, int n_in,
                              void* d_out, int out_size, void* d_ws, size_t ws_size,
                              hipStream_t stream) {
  const float* feat = (const float*)d_in[0];
  const int* dom = (const int*)d_in[1];
  float* out = (float*)d_out;
  const int N = in_sizes[1];
  const int D = in_sizes[0] / N;
  const int T = N / 128;
  const int nblk = T * (T + 1) / 2;

  char* ws = (char*)d_ws;
  float2* partial = (float2*)ws;                       // 8*nblk B
  float* sqpart = (float*)(ws + 16640);                // 4*N floats
  uint4* fbt = (uint4*)(ws + 82176);                   // 2*N*D B, 16-aligned

  prep_kernel<<<dim3((N / 64) * 4), dim3(256), 0, stream>>>(feat, fbt, sqpart, N, D);
  mmd_main<<<dim3(nblk), dim3(512), 0, stream>>>(fbt, sqpart, dom, partial, N);
  finalize_kernel<<<1, 256, 0, stream>>>(partial, nblk, dom, out, N);
}